// Round 10
// baseline (370.658 us; speedup 1.0000x reference)
//
#include <hip/hip_runtime.h>
#include <math.h>

#define T_LEN 100
#define K_LEN 25
#define DLAT 64
#define DHID 128
#define CST 68   // h2s/aggs row stride (floats)
#define AST 68   // adjacency row stride (u32)

// LDS carve: h2s(4352f) + aggs(4352f) + Asu(4352u32) = 52224 B (r3-identical).
// Tail overlays (all regions dead after part2):
//   SQl/QQl -> Asu area, Pred -> h2s area, red -> aggs area.

// Full-grid barrier. SAFE: grid = G <= 512; launch_bounds(512,4) caps VGPR at
// 128 -> >=16 waves/CU -> >=2 blocks/CU x 256 CUs = 512 resident before any
// block waits. r7 run confirmed this barrier completes on this exact grid.
__device__ __forceinline__ void gbar(unsigned* cnt, unsigned* flag,
                                     unsigned nb) {
    __syncthreads();
    if (threadIdx.x == 0) {
        __threadfence();
        unsigned t = __hip_atomic_fetch_add(cnt, 1u, __ATOMIC_ACQ_REL,
                                            __HIP_MEMORY_SCOPE_AGENT);
        if (t == nb - 1u) {
            __hip_atomic_store(flag, 1u, __ATOMIC_RELEASE,
                               __HIP_MEMORY_SCOPE_AGENT);
        } else {
            while (__hip_atomic_load(flag, __ATOMIC_ACQUIRE,
                                     __HIP_MEMORY_SCOPE_AGENT) == 0u)
                __builtin_amdgcn_s_sleep(8);
        }
        __threadfence();
    }
    __syncthreads();
}

// ---------------------------------------------------------------------------
// packU: Wm[c*100+i] = collapsed Conv1d+fc1 matrix; Wm[6400+c] = b2[c];
//        bar[0..7] = 0 (grid-barrier state, rezeroed every launch/replay)
// ---------------------------------------------------------------------------
__global__ __launch_bounds__(256) void packU(const float* __restrict__ conv_w,
                                             const float* __restrict__ conv_b,
                                             const float* __restrict__ fc1_w,
                                             const float* __restrict__ fc1_b,
                                             float* __restrict__ Wm,
                                             unsigned* __restrict__ bar) {
    int idx = blockIdx.x * 256 + threadIdx.x;
    if (idx < 6400) {
        int c = idx / T_LEN, i = idx % T_LEN;
        int t0 = i - 12 > 0 ? i - 12 : 0;
        int t1 = i + 12 < T_LEN - 1 ? i + 12 : T_LEN - 1;
        float acc = 0.f;
        for (int t = t0; t <= t1; ++t)
            acc += fc1_w[t] * conv_w[c * K_LEN + (i - t + 12)];
        Wm[idx] = acc;
    } else if (idx < 6400 + 64) {
        int c = idx - 6400;
        float S = 0.f;
        for (int t = 0; t < T_LEN; ++t) S += fc1_w[t];
        Wm[6400 + c] = conv_b[c] * S + fc1_b[0];
    } else if (idx < 6400 + 64 + 8) {
        bar[idx - 6400 - 64] = 0u;
    }
}

// ---------------------------------------------------------------------------
// fused: r3's proven phase bodies (87-98 us lineage), occupancy UNPINNED via
// (512,4) [r3's (512,2) pinned 21.6%; r2 at (512,4) measured 39%], plus the
// r7-proven grid-barrier D/E tail (saves 2 launches).
//   0 issue 2048 strided edge loads -> regs
//   1 encoder: lane=node, W via wave-uniform s_load stream -> h2s      S1
//   2 LDS-atomic edge count                                            S2
//   3 agg = A @ h2 (counts converted inline)                           S3
//   4 part2: wave owns j in [16w,16w+16); acc[16]; mc chunks of 8;
//     weights as 32B uniform runs; shfl-reduce moments -> Sg/Qg (+LDS)
//   5 gbar -> D (BN stats, 128 blocks) -> gbar -> E (head, per block)
// ---------------------------------------------------------------------------
__global__ __launch_bounds__(512, 4) void fused(const float* __restrict__ x,
                                                const int* __restrict__ ei,
                                                const float* __restrict__ Wm,
                                                const float* __restrict__ rel_w,
                                                const float* __restrict__ rel_b,
                                                const float* __restrict__ root_w,
                                                const float* __restrict__ gamma,
                                                const float* __restrict__ beta,
                                                const float* __restrict__ fc2_w,
                                                const float* __restrict__ fc2_b,
                                                float* __restrict__ Sg,
                                                float* __restrict__ Qg,
                                                float* __restrict__ abG,
                                                float* __restrict__ y,
                                                unsigned* __restrict__ bar,
                                                int E, int G, int N, int coop) {
    __shared__ float h2s[64 * CST];
    __shared__ float aggs[64 * CST];
    __shared__ unsigned Asu[64 * AST];

    float* SQl = (float*)Asu;          // 128 f (post-part2)
    float* QQl = (float*)Asu + 128;    // 128 f
    float* Pred = h2s;                 // 384 f (tail E)
    float* red = aggs;                 // 16 f (tail D)

    const int tid = threadIdx.x;
    const int lane = tid & 63;
    const int w2 = __builtin_amdgcn_readfirstlane(tid >> 6);  // 0..7 uniform

    // bijective XCD swizzle (m204)
    const int nb = gridDim.x;
    int qq = nb >> 3, rr = nb & 7;
    int xc = blockIdx.x & 7, oo = blockIdx.x >> 3;
    const int g = (xc < rr ? xc * (qq + 1) : rr * (qq + 1) + (xc - rr) * qq) + oo;

    const int epg = (G > 0) ? E / G : 0;
    const bool fast = (epg == 2048) && (E == G * 2048);

    // ---- 0. issue strided edge loads EARLY (drain after encoder) ----
    int es0 = 0, es1 = 0, es2 = 0, es3 = 0;
    int ed0 = 0, ed1 = 0, ed2 = 0, ed3 = 0;
    if (fast) {
        int e0 = g + tid * G;
        int st = 512 * G;
        es0 = ei[e0];           ed0 = ei[E + e0];
        es1 = ei[e0 + st];      ed1 = ei[E + e0 + st];
        es2 = ei[e0 + 2 * st];  ed2 = ei[E + e0 + 2 * st];
        es3 = ei[e0 + 3 * st];  ed3 = ei[E + e0 + 3 * st];
    }

    // zero adjacency counters (disjoint from encoder's h2s writes)
    for (int i = tid; i < 64 * AST; i += 512) Asu[i] = 0u;

    // ---- 1. encoder: lane=node; wave w2 -> channels [8w2, 8w2+8) ----
    {
        const float4* __restrict__ xp =
            (const float4*)(x + (size_t)(g * 64 + lane) * T_LEN);
        const float* Wb = Wm + w2 * 8 * T_LEN;  // wave-uniform -> s_load
        float acc[8];
#pragma unroll
        for (int c = 0; c < 8; ++c) acc[c] = 0.f;
#pragma unroll
        for (int tq = 0; tq < T_LEN / 4; ++tq) {
            float4 xv = xp[tq];
#pragma unroll
            for (int c = 0; c < 8; ++c) {
                const float* wr = Wb + c * T_LEN + tq * 4;
                acc[c] += xv.x * wr[0] + xv.y * wr[1] + xv.z * wr[2] + xv.w * wr[3];
            }
        }
        float4 o0, o1;
        o0.x = acc[0] + Wm[6400 + w2 * 8 + 0];
        o0.y = acc[1] + Wm[6400 + w2 * 8 + 1];
        o0.z = acc[2] + Wm[6400 + w2 * 8 + 2];
        o0.w = acc[3] + Wm[6400 + w2 * 8 + 3];
        o1.x = acc[4] + Wm[6400 + w2 * 8 + 4];
        o1.y = acc[5] + Wm[6400 + w2 * 8 + 5];
        o1.z = acc[6] + Wm[6400 + w2 * 8 + 6];
        o1.w = acc[7] + Wm[6400 + w2 * 8 + 7];
        *(float4*)&h2s[lane * CST + w2 * 8] = o0;
        *(float4*)&h2s[lane * CST + w2 * 8 + 4] = o1;
    }
    __syncthreads();  // S1

    // ---- 2. edge counting via LDS atomics ----
    if (fast) {
        atomicAdd(&Asu[(ed0 & 63) * AST + (es0 & 63)], 1u);
        atomicAdd(&Asu[(ed1 & 63) * AST + (es1 & 63)], 1u);
        atomicAdd(&Asu[(ed2 & 63) * AST + (es2 & 63)], 1u);
        atomicAdd(&Asu[(ed3 & 63) * AST + (es3 & 63)], 1u);
    } else {
        for (int e = g + tid * G; e < E; e += 512 * G)
            atomicAdd(&Asu[(ei[E + e] & 63) * AST + (ei[e] & 63)], 1u);
    }
    __syncthreads();  // S2

    // ---- 3. agg = A @ h2 (counts converted inline); thread: (n, n+32) x 4ch ----
    {
        int c4 = (tid & 15) * 4;
        int n0 = tid >> 4;  // 0..31
#pragma unroll
        for (int i = 0; i < 2; ++i) {
            int n = n0 + 32 * i;
            float4 a4 = {0.f, 0.f, 0.f, 0.f};
#pragma unroll 4
            for (int s4 = 0; s4 < 16; ++s4) {
                uint4 au = *(const uint4*)&Asu[n * AST + 4 * s4];
                float a0 = (float)au.x, a1 = (float)au.y;
                float a2 = (float)au.z, a3 = (float)au.w;
                float4 h0 = *(const float4*)&h2s[(4 * s4 + 0) * CST + c4];
                float4 h1 = *(const float4*)&h2s[(4 * s4 + 1) * CST + c4];
                float4 h2v = *(const float4*)&h2s[(4 * s4 + 2) * CST + c4];
                float4 h3 = *(const float4*)&h2s[(4 * s4 + 3) * CST + c4];
                a4.x += a0 * h0.x + a1 * h1.x + a2 * h2v.x + a3 * h3.x;
                a4.y += a0 * h0.y + a1 * h1.y + a2 * h2v.y + a3 * h3.y;
                a4.z += a0 * h0.z + a1 * h1.z + a2 * h2v.z + a3 * h3.z;
                a4.w += a0 * h0.w + a1 * h1.w + a2 * h2v.w + a3 * h3.w;
            }
            *(float4*)&aggs[n * CST + c4] = a4;
        }
    }
    __syncthreads();  // S3

    // ---- 4. part2: wave w2 owns j in [16w2,16w2+16); acc[16]; mc chunks of 8 ----
    {
        float acc[16];
#pragma unroll
        for (int ji = 0; ji < 16; ++ji) acc[ji] = 0.f;

#pragma unroll
        for (int mc = 0; mc < 8; ++mc) {
            float4 za0 = *(const float4*)&aggs[lane * CST + mc * 8];
            float4 za1 = *(const float4*)&aggs[lane * CST + mc * 8 + 4];
            float4 zh0 = *(const float4*)&h2s[lane * CST + mc * 8];
            float4 zh1 = *(const float4*)&h2s[lane * CST + mc * 8 + 4];
#pragma unroll
            for (int ji = 0; ji < 16; ++ji) {
                int j = w2 * 16 + ji;  // uniform
                const float* rp = rel_w + (size_t)j * DLAT + mc * 8;   // 32B run
                const float* op = root_w + (size_t)j * DLAT + mc * 8;
                float a = acc[ji];
                a += za0.x * rp[0] + za0.y * rp[1] + za0.z * rp[2] + za0.w * rp[3];
                a += za1.x * rp[4] + za1.y * rp[5] + za1.z * rp[6] + za1.w * rp[7];
                a += zh0.x * op[0] + zh0.y * op[1] + zh0.z * op[2] + zh0.w * op[3];
                a += zh1.x * op[4] + zh1.y * op[5] + zh1.z * op[6] + zh1.w * op[7];
                acc[ji] = a;
            }
        }
        __syncthreads();  // aggs/h2s/Asu reads done -> overlays become legal

#pragma unroll
        for (int ji = 0; ji < 16; ++ji) {
            int j = w2 * 16 + ji;
            float outv = acc[ji] + rel_b[j];
            float sq = outv * outv;
#pragma unroll
            for (int off = 32; off; off >>= 1) {
                outv += __shfl_xor(outv, off);
                sq += __shfl_xor(sq, off);
            }
            if (lane == 0) {
                Sg[(size_t)g * DHID + j] = outv;
                Qg[(size_t)g * DHID + j] = sq;
                SQl[j] = outv;   // stash for tail E (overlays dead Asu)
                QQl[j] = sq;
            }
        }
    }

    if (!coop) return;  // host fallback runs D/E

    gbar(&bar[0], &bar[1], (unsigned)nb);  // Sg/Qg visible device-wide

    // ---- D: blocks 0..127 compute BN scale/shift for channel j=bid ----
    if (blockIdx.x < DHID) {
        int j = blockIdx.x;
        float s = 0.f, qv = 0.f;
        for (int gi = tid; gi < G; gi += 512) {
            s += Sg[(size_t)gi * DHID + j];
            qv += Qg[(size_t)gi * DHID + j];
        }
#pragma unroll
        for (int off = 32; off; off >>= 1) {
            s += __shfl_xor(s, off);
            qv += __shfl_xor(qv, off);
        }
        if ((tid & 63) == 0) { red[w2] = s; red[8 + w2] = qv; }
        __syncthreads();
        if (tid == 0) {
            s = 0.f; qv = 0.f;
#pragma unroll
            for (int k = 0; k < 8; ++k) { s += red[k]; qv += red[8 + k]; }
            float inv_n = 1.f / (float)N;
            float mean = s * inv_n;
            float var = qv * inv_n - mean * mean;
            float a = rsqrtf(var + 1e-5f) * gamma[j];
            float b = beta[j] - mean * a;
            abG[j] = a;
            abG[DHID + j] = b;
        }
    }

    gbar(&bar[2], &bar[3], (unsigned)nb);  // abG visible device-wide

    // ---- E: per-block head from LDS-stashed S/Q ----
    if (tid < DHID) {
        int j = tid;
        float a = abG[j], b = abG[DHID + j];
        float S = SQl[j], Q = QQl[j];
        float pooled = (a * a * Q + 2.f * a * b * S) * (1.f / 64.f) + b * b;
        float pl = logf(fmaxf(pooled, 1e-6f));
        Pred[j] = pl * fc2_w[j];
        Pred[128 + j] = pl * fc2_w[DHID + j];
        Pred[256 + j] = pl * fc2_w[2 * DHID + j];
    }
    __syncthreads();
    if (tid < 3) {
        float v = fc2_b[tid];
        for (int c = 0; c < DHID; ++c) v += Pred[tid * 128 + c];
        y[(size_t)g * 3 + tid] = 1.f / (1.f + expf(-v));
    }
}

// ---------------------------------------------------------------------------
// Fallback D/E (only if grid can't co-reside -> coop=0; not hit at G=512)
// ---------------------------------------------------------------------------
__global__ __launch_bounds__(256) void phaseD2(const float* __restrict__ Sg,
                                               const float* __restrict__ Qg,
                                               const float* __restrict__ gamma,
                                               const float* __restrict__ beta,
                                               float* __restrict__ ab,
                                               int G, int N) {
    int j = blockIdx.x;
    int t = threadIdx.x;
    float s = 0.f, q = 0.f;
    for (int g = t; g < G; g += 256) {
        s += Sg[g * DHID + j];
        q += Qg[g * DHID + j];
    }
#pragma unroll
    for (int off = 32; off; off >>= 1) {
        s += __shfl_xor(s, off);
        q += __shfl_xor(q, off);
    }
    __shared__ float rs[4], rq[4];
    int wv = t >> 6;
    if ((t & 63) == 0) { rs[wv] = s; rq[wv] = q; }
    __syncthreads();
    if (t == 0) {
        s = rs[0] + rs[1] + rs[2] + rs[3];
        q = rq[0] + rq[1] + rq[2] + rq[3];
        float inv_n = 1.f / (float)N;
        float mean = s * inv_n;
        float var = q * inv_n - mean * mean;
        float a = rsqrtf(var + 1e-5f) * gamma[j];
        float b = beta[j] - mean * a;
        ab[j] = a;
        ab[DHID + j] = b;
    }
}

__global__ __launch_bounds__(128) void phaseE(const float* __restrict__ Sg,
                                              const float* __restrict__ Qg,
                                              const float* __restrict__ ab,
                                              const float* __restrict__ fc2_w,
                                              const float* __restrict__ fc2_b,
                                              float* __restrict__ y) {
    int g = blockIdx.x;
    int j = threadIdx.x;
    __shared__ float ps[DHID];
    float a = ab[j], b = ab[DHID + j];
    float S = Sg[g * DHID + j], Q = Qg[g * DHID + j];
    float pooled = (a * a * Q + 2.f * a * b * S) * (1.f / 64.f) + b * b;
    pooled = fmaxf(pooled, 1e-6f);
    ps[j] = logf(pooled);
    __syncthreads();
    if (j < 3) {
        float acc = fc2_b[j];
        for (int c = 0; c < DHID; ++c) acc += ps[c] * fc2_w[j * DHID + c];
        y[g * 3 + j] = 1.f / (1.f + expf(-acc));
    }
}

// ---------------------------------------------------------------------------
extern "C" void kernel_launch(void* const* d_in, const int* in_sizes, int n_in,
                              void* d_out, int out_size, void* d_ws, size_t ws_size,
                              hipStream_t stream) {
    const float* x      = (const float*)d_in[0];
    const int*   ei     = (const int*)d_in[1];
    const float* conv_w = (const float*)d_in[3];
    const float* conv_b = (const float*)d_in[4];
    const float* fc1_w  = (const float*)d_in[5];
    const float* fc1_b  = (const float*)d_in[6];
    const float* rel_w  = (const float*)d_in[7];
    const float* rel_b  = (const float*)d_in[8];
    const float* root_w = (const float*)d_in[9];
    const float* gamma  = (const float*)d_in[10];
    const float* beta   = (const float*)d_in[11];
    const float* fc2_w  = (const float*)d_in[12];
    const float* fc2_b  = (const float*)d_in[13];
    float* y = (float*)d_out;

    int N = in_sizes[2];       // 32768
    int E = in_sizes[1] / 2;   // 1048576
    int G = N / 64;            // 512

    float* Sg     = (float*)d_ws;                  // G*128
    float* Qg     = Sg + (size_t)G * DHID;         // G*128
    float* Wm     = Qg + (size_t)G * DHID;         // 6464
    float* abG    = Wm + 6464;                     // 256
    unsigned* bar = (unsigned*)(abG + 256);        // 8

    int coop = (G <= 512) ? 1 : 0;

    packU<<<26, 256, 0, stream>>>(conv_w, conv_b, fc1_w, fc1_b, Wm, bar);
    fused<<<G, 512, 0, stream>>>(x, ei, Wm, rel_w, rel_b, root_w,
                                 gamma, beta, fc2_w, fc2_b,
                                 Sg, Qg, abG, y, bar, E, G, N, coop);
    if (!coop) {
        phaseD2<<<DHID, 256, 0, stream>>>(Sg, Qg, gamma, beta, abG, G, N);
        phaseE<<<G, DHID, 0, stream>>>(Sg, Qg, abG, fc2_w, fc2_b, y);
    }
}

// Round 11
// 175.661 us; speedup vs baseline: 2.1101x; 2.1101x over previous
//
#include <hip/hip_runtime.h>
#include <math.h>

#define T_LEN 100
#define K_LEN 25
#define DLAT 64
#define DHID 128
#define CST 68
#define AST 68

// ---------------------------------------------------------------------------
// buildW: collapse Conv1d(1,64,25,pad=12) + Linear(100,1) into one matrix:
//   h2[n,c] = sum_i x[n,i] * W[c,i] + b2[c]
// ---------------------------------------------------------------------------
__global__ __launch_bounds__(256) void buildW(const float* __restrict__ conv_w,
                                              const float* __restrict__ conv_b,
                                              const float* __restrict__ fc1_w,
                                              const float* __restrict__ fc1_b,
                                              float* __restrict__ W,
                                              float* __restrict__ b2) {
    int idx = blockIdx.x * 256 + threadIdx.x;
    if (idx < 64 * T_LEN) {
        int c = idx / T_LEN, i = idx % T_LEN;
        int t0 = i - 12 > 0 ? i - 12 : 0;
        int t1 = i + 12 < T_LEN - 1 ? i + 12 : T_LEN - 1;
        float acc = 0.f;
        for (int t = t0; t <= t1; ++t)
            acc += fc1_w[t] * conv_w[c * K_LEN + (i - t + 12)];
        W[idx] = acc;
    } else if (idx < 64 * T_LEN + 64) {
        int c = idx - 64 * T_LEN;
        float S = 0.f;
        for (int t = 0; t < T_LEN; ++t) S += fc1_w[t];
        b2[c] = conv_b[c] * S + fc1_b[0];
    }
}

// ---------------------------------------------------------------------------
// phaseCF4: r2's proven fused kernel (87 us measured WITH 44MB spill), with
// part2's live set reduced below the (512,4) allocator's ~56-VGPR spill
// threshold: channel chunks of 8 (za0/za1/zh0/zh1 = 16 live floats) instead
// of 16 (za[4]/zh[4] = 32 live), jb=2 halves with acc[8].
//   0 issue this graph's 2048 strided edge loads (latency hidden under 1.)
//   1 h2 (encoder) straight into LDS; W on the uniform s_load path
//   2 LDS-atomic 64x64 adjacency count
//   3 agg = A @ h2 (u32 counts converted inline)
//   4 out = agg.rel^T + h2.root^T + rel_b -> Sg/Qg moments via shfl reduce
// ---------------------------------------------------------------------------
__global__ __launch_bounds__(512, 4) void phaseCF4(const float* __restrict__ x,
                                                   const int* __restrict__ ei,
                                                   const float* __restrict__ Wm,
                                                   const float* __restrict__ b2,
                                                   const float* __restrict__ rel_w,
                                                   const float* __restrict__ rel_b,
                                                   const float* __restrict__ root_w,
                                                   float* __restrict__ Sg,
                                                   float* __restrict__ Qg,
                                                   int E, int G) {
    __shared__ float h2s[64 * CST];
    __shared__ float aggs[64 * CST];
    __shared__ unsigned Asu[64 * AST];

    int tid = threadIdx.x;
    int bid = blockIdx.x;
    int lane = tid & 63;
    int w = __builtin_amdgcn_readfirstlane(tid >> 6);  // 0..7, uniform

    // bijective XCD swizzle (m204): graphs sharing edge cachelines land on
    // the same XCD so the stride-G edge reads are L2 hits.
    int q = G >> 3, r = G & 7;
    int xc = bid & 7, o = bid >> 3;
    int g = (xc < r ? xc * (q + 1) : r * (q + 1) + (xc - r) * q) + o;

    int epg = E / G;
    bool fast = (epg == 2048);

    // 0. issue strided edge loads EARLY; the vmcnt wait lands after the
    // encoder loop, so HBM/L2 latency hides under phase 1 compute.
    int es0 = 0, es1 = 0, es2 = 0, es3 = 0;
    int ed0 = 0, ed1 = 0, ed2 = 0, ed3 = 0;
    if (fast) {
        int e0 = g + tid * G;
        int st = 512 * G;
        es0 = ei[e0];            ed0 = ei[E + e0];
        es1 = ei[e0 + st];       ed1 = ei[E + e0 + st];
        es2 = ei[e0 + 2 * st];   ed2 = ei[E + e0 + 2 * st];
        es3 = ei[e0 + 3 * st];   ed3 = ei[E + e0 + 3 * st];
    }

    // zero adjacency counters
    for (int idx = tid; idx < 64 * AST; idx += 512) Asu[idx] = 0u;

    // 1. encoder: h2s[lane][8w..8w+8)
    {
        const float4* __restrict__ xp =
            (const float4*)(x + (size_t)(g * 64 + lane) * T_LEN);
        const float* __restrict__ Wb = Wm + w * 8 * T_LEN;  // uniform
        float acc[8];
#pragma unroll
        for (int c = 0; c < 8; ++c) acc[c] = 0.f;
#pragma unroll
        for (int tq = 0; tq < T_LEN / 4; ++tq) {
            float4 xv = xp[tq];
#pragma unroll
            for (int c = 0; c < 8; ++c) {
                const float* wr = Wb + c * T_LEN + tq * 4;  // uniform -> s_load
                acc[c] += xv.x * wr[0] + xv.y * wr[1] + xv.z * wr[2] + xv.w * wr[3];
            }
        }
        float4 o0, o1;
        o0.x = acc[0] + b2[w * 8 + 0];
        o0.y = acc[1] + b2[w * 8 + 1];
        o0.z = acc[2] + b2[w * 8 + 2];
        o0.w = acc[3] + b2[w * 8 + 3];
        o1.x = acc[4] + b2[w * 8 + 4];
        o1.y = acc[5] + b2[w * 8 + 5];
        o1.z = acc[6] + b2[w * 8 + 6];
        o1.w = acc[7] + b2[w * 8 + 7];
        *(float4*)&h2s[lane * CST + w * 8] = o0;
        *(float4*)&h2s[lane * CST + w * 8 + 4] = o1;
    }
    __syncthreads();

    // 2. edge counting via LDS atomics
    if (fast) {
        atomicAdd(&Asu[(ed0 & 63) * AST + (es0 & 63)], 1u);
        atomicAdd(&Asu[(ed1 & 63) * AST + (es1 & 63)], 1u);
        atomicAdd(&Asu[(ed2 & 63) * AST + (es2 & 63)], 1u);
        atomicAdd(&Asu[(ed3 & 63) * AST + (es3 & 63)], 1u);
    } else {
        for (int k = tid; k < epg; k += 512) {
            int e = g + k * G;
            atomicAdd(&Asu[(ei[E + e] & 63) * AST + (ei[e] & 63)], 1u);
        }
    }
    __syncthreads();

    // 3. agg = A @ h2 (convert counts inline). thread owns (n, n+32) x 4 ch.
    {
        int c4 = (tid & 15) * 4;
        int n0 = tid >> 4;  // 0..31
#pragma unroll
        for (int i = 0; i < 2; ++i) {
            int n = n0 + 32 * i;
            float4 a4 = {0.f, 0.f, 0.f, 0.f};
#pragma unroll 4
            for (int s4 = 0; s4 < 16; ++s4) {
                uint4 au = *(const uint4*)&Asu[n * AST + 4 * s4];
                float a0 = (float)au.x, a1 = (float)au.y;
                float a2 = (float)au.z, a3 = (float)au.w;
                float4 h0 = *(const float4*)&h2s[(4 * s4 + 0) * CST + c4];
                float4 h1 = *(const float4*)&h2s[(4 * s4 + 1) * CST + c4];
                float4 h2v = *(const float4*)&h2s[(4 * s4 + 2) * CST + c4];
                float4 h3 = *(const float4*)&h2s[(4 * s4 + 3) * CST + c4];
                a4.x += a0 * h0.x + a1 * h1.x + a2 * h2v.x + a3 * h3.x;
                a4.y += a0 * h0.y + a1 * h1.y + a2 * h2v.y + a3 * h3.y;
                a4.z += a0 * h0.z + a1 * h1.z + a2 * h2v.z + a3 * h3.z;
                a4.w += a0 * h0.w + a1 * h1.w + a2 * h2v.w + a3 * h3.w;
            }
            *(float4*)&aggs[n * CST + c4] = a4;
        }
    }
    __syncthreads();

    // 4. part2: wave w owns j in [16w,16w+16), jb halves of 8 j's,
    //    channel chunks of 8 floats -> 16 live z floats + acc[8]:
    //    fits the (512,4) allocator's 56-64 VGPR choice WITHOUT spill
    //    (r2's 16-float chunks spilled 44MB; r10's acc[16] spilled 32MB).
#pragma unroll
    for (int jb = 0; jb < 2; ++jb) {
        float acc[8];
#pragma unroll
        for (int ji = 0; ji < 8; ++ji) acc[ji] = 0.f;

#pragma unroll
        for (int mc = 0; mc < 8; ++mc) {
            float4 za0 = *(const float4*)&aggs[lane * CST + mc * 8];
            float4 za1 = *(const float4*)&aggs[lane * CST + mc * 8 + 4];
            float4 zh0 = *(const float4*)&h2s[lane * CST + mc * 8];
            float4 zh1 = *(const float4*)&h2s[lane * CST + mc * 8 + 4];
#pragma unroll
            for (int ji = 0; ji < 8; ++ji) {
                int j = w * 16 + jb * 8 + ji;  // uniform
                const float* rp = rel_w + (size_t)j * DLAT + mc * 8;   // 32B run
                const float* op = root_w + (size_t)j * DLAT + mc * 8;
                float a = acc[ji];
                a += za0.x * rp[0] + za0.y * rp[1] + za0.z * rp[2] + za0.w * rp[3];
                a += za1.x * rp[4] + za1.y * rp[5] + za1.z * rp[6] + za1.w * rp[7];
                a += zh0.x * op[0] + zh0.y * op[1] + zh0.z * op[2] + zh0.w * op[3];
                a += zh1.x * op[4] + zh1.y * op[5] + zh1.z * op[6] + zh1.w * op[7];
                acc[ji] = a;
            }
        }

#pragma unroll
        for (int ji = 0; ji < 8; ++ji) {
            int j = w * 16 + jb * 8 + ji;
            float outv = acc[ji] + rel_b[j];
            float sq = outv * outv;
#pragma unroll
            for (int off = 32; off; off >>= 1) {
                outv += __shfl_xor(outv, off);
                sq += __shfl_xor(sq, off);
            }
            if (lane == 0) {
                Sg[g * DHID + j] = outv;
                Qg[g * DHID + j] = sq;
            }
        }
    }
}

// ---------------------------------------------------------------------------
// Phase D: BN stats per channel -> a[j], b[j] (scale/shift)
// ---------------------------------------------------------------------------
__global__ __launch_bounds__(256) void phaseD2(const float* __restrict__ Sg,
                                               const float* __restrict__ Qg,
                                               const float* __restrict__ gamma,
                                               const float* __restrict__ beta,
                                               float* __restrict__ ab,
                                               int G, int N) {
    int j = blockIdx.x;
    int t = threadIdx.x;
    float s = 0.f, q = 0.f;
    for (int g = t; g < G; g += 256) {
        s += Sg[g * DHID + j];
        q += Qg[g * DHID + j];
    }
#pragma unroll
    for (int off = 32; off; off >>= 1) {
        s += __shfl_xor(s, off);
        q += __shfl_xor(q, off);
    }
    __shared__ float rs[4], rq[4];
    int wv = t >> 6;
    if ((t & 63) == 0) { rs[wv] = s; rq[wv] = q; }
    __syncthreads();
    if (t == 0) {
        s = rs[0] + rs[1] + rs[2] + rs[3];
        q = rq[0] + rq[1] + rq[2] + rq[3];
        float inv_n = 1.f / (float)N;
        float mean = s * inv_n;
        float var = q * inv_n - mean * mean;
        float a = rsqrtf(var + 1e-5f) * gamma[j];
        float b = beta[j] - mean * a;
        ab[j] = a;
        ab[DHID + j] = b;
    }
}

// ---------------------------------------------------------------------------
// Phase E: pooled = (a^2 Q + 2ab S)/64 + b^2 ; log(clamp) ; fc2 ; sigmoid
// ---------------------------------------------------------------------------
__global__ __launch_bounds__(128) void phaseE(const float* __restrict__ Sg,
                                              const float* __restrict__ Qg,
                                              const float* __restrict__ ab,
                                              const float* __restrict__ fc2_w,
                                              const float* __restrict__ fc2_b,
                                              float* __restrict__ y) {
    int g = blockIdx.x;
    int j = threadIdx.x;
    __shared__ float ps[DHID];
    float a = ab[j], b = ab[DHID + j];
    float S = Sg[g * DHID + j], Q = Qg[g * DHID + j];
    float pooled = (a * a * Q + 2.f * a * b * S) * (1.f / 64.f) + b * b;
    pooled = fmaxf(pooled, 1e-6f);
    ps[j] = logf(pooled);
    __syncthreads();
    if (j < 3) {
        float acc = fc2_b[j];
        for (int c = 0; c < DHID; ++c) acc += ps[c] * fc2_w[j * DHID + c];
        y[g * 3 + j] = 1.f / (1.f + expf(-acc));
    }
}

// ---------------------------------------------------------------------------
extern "C" void kernel_launch(void* const* d_in, const int* in_sizes, int n_in,
                              void* d_out, int out_size, void* d_ws, size_t ws_size,
                              hipStream_t stream) {
    const float* x      = (const float*)d_in[0];
    const int*   ei     = (const int*)d_in[1];
    const float* conv_w = (const float*)d_in[3];
    const float* conv_b = (const float*)d_in[4];
    const float* fc1_w  = (const float*)d_in[5];
    const float* fc1_b  = (const float*)d_in[6];
    const float* rel_w  = (const float*)d_in[7];
    const float* rel_b  = (const float*)d_in[8];
    const float* root_w = (const float*)d_in[9];
    const float* gamma  = (const float*)d_in[10];
    const float* beta   = (const float*)d_in[11];
    const float* fc2_w  = (const float*)d_in[12];
    const float* fc2_b  = (const float*)d_in[13];
    float* y = (float*)d_out;

    int N = in_sizes[2];       // 32768
    int E = in_sizes[1] / 2;   // 1048576
    int G = N / 64;            // 512

    float* Sg = (float*)d_ws;                  // G*128
    float* Qg = Sg + (size_t)G * DHID;         // G*128
    float* ab = Qg + (size_t)G * DHID;         // 2*128
    float* Wm = ab + 2 * DHID;                 // 64*100
    float* b2 = Wm + 64 * T_LEN;               // 64

    buildW<<<26, 256, 0, stream>>>(conv_w, conv_b, fc1_w, fc1_b, Wm, b2);
    phaseCF4<<<G, 512, 0, stream>>>(x, ei, Wm, b2, rel_w, rel_b, root_w,
                                    Sg, Qg, E, G);
    phaseD2<<<DHID, 256, 0, stream>>>(Sg, Qg, gamma, beta, ab, G, N);
    phaseE<<<G, DHID, 0, stream>>>(Sg, Qg, ab, fc2_w, fc2_b, y);
}